// Round 1
// baseline (571.034 us; speedup 1.0000x reference)
//
#include <hip/hip_runtime.h>

// ItemRegressionModel: out[b] = bu + bt + (1/32) * sum_k w[qtu_k, t] * (r[u, qtu_k] - bu - b_item[qtu_k])
// U=I=2000, K=32, B=16384.
// Mapping: 32 lanes per sample. qtus load is coalesced (128B contiguous per
// sample); weight/rating/b_item are random gathers served by L1/L2 (16MB each).

#define U_DIM 2000
#define I_DIM 2000
#define K_DIM 32

__global__ __launch_bounds__(256) void irm_kernel(
    const float* __restrict__ rating,   // (U, I)
    const int*   __restrict__ qtus,     // (U, I, K)
    const float* __restrict__ weight,   // (I, I)
    const float* __restrict__ b_user,   // (U,)
    const float* __restrict__ b_item,   // (I,)
    const int*   __restrict__ users,    // (B,)
    const int*   __restrict__ items,    // (B,)
    float*       __restrict__ out,      // (B,)
    int B)
{
    const int tid = blockIdx.x * blockDim.x + threadIdx.x;
    const int b = tid >> 5;      // sample index
    const int k = tid & 31;      // neighborhood slot
    if (b >= B) return;

    const int u = users[b];
    const int t = items[b];

    const size_t qbase = ((size_t)u * I_DIM + t) * (size_t)K_DIM;
    const int j = qtus[qbase + (size_t)k];          // coalesced: lane k -> word k

    const float w  = weight[(size_t)j * I_DIM + t]; // gather: column t, random row
    const float r  = rating[(size_t)u * I_DIM + j]; // gather: row u, random col
    const float bu = b_user[u];
    const float bj = b_item[j];                     // 8KB table, cache-resident

    float v = w * (r - bu - bj);

    // reduce across the 32 lanes of this sample (wave=64 holds 2 samples;
    // xor-shuffles with width 32 stay within each half)
    #pragma unroll
    for (int off = 16; off; off >>= 1)
        v += __shfl_xor(v, off, 32);

    if (k == 0)
        out[b] = bu + b_item[t] + v * (1.0f / 32.0f);
}

extern "C" void kernel_launch(void* const* d_in, const int* in_sizes, int n_in,
                              void* d_out, int out_size, void* d_ws, size_t ws_size,
                              hipStream_t stream)
{
    const float* rating = (const float*)d_in[0];
    const int*   qtus   = (const int*)  d_in[1];
    const float* weight = (const float*)d_in[2];
    const float* b_user = (const float*)d_in[3];
    const float* b_item = (const float*)d_in[4];
    const int*   users  = (const int*)  d_in[5];
    const int*   items  = (const int*)  d_in[6];
    float*       out    = (float*)d_out;

    const int B = in_sizes[5];           // users count = 16384
    const int threads = 256;
    const int total = B * 32;
    const int blocks = (total + threads - 1) / threads;
    irm_kernel<<<blocks, threads, 0, stream>>>(rating, qtus, weight, b_user,
                                               b_item, users, items, out, B);
}